// Round 5
// baseline (2380.523 us; speedup 1.0000x reference)
//
#include <hip/hip_runtime.h>
#include <math.h>

#define EMBED   2048
#define NEXP    64
#define BATCHN  16384
#define MTILE   32
#define KCH     64
#define NCHUNK  (EMBED / KCH)   // 32
#define WPAD    68              // W LDS row stride (floats): 16B-aligned, 2-way-max banking
#define NT_A    256
#define NT_B    256
#define MARGIN_THRESH 4e-4f     // fp32 logit error tail ~1e-5; 40x safety margin

// ---------------- Kernel A: fp32 GEMM + top-2 + gates + near-tie flags ----------------
__global__ __launch_bounds__(NT_A, 2)
void gemm_topk_kernel(const float* __restrict__ x, const float* __restrict__ W,
                      const float* __restrict__ bias, float* __restrict__ out,
                      int* __restrict__ flags)
{
    __shared__ __align__(16) float xs[2][MTILE * KCH];    // 16 KB
    __shared__ __align__(16) float ws[2][NEXP * WPAD];    // 34.8 KB

    const int tid  = threadIdx.x;
    const int er   = tid & 15;            // expert group: experts er + 16j, j<4
    const int rr   = tid >> 4;            // row group 0..15: rows rr*2 + i
    const int row0 = blockIdx.x * MTILE;

    float acc[2][4] = {};
    float4 xreg[2], wreg[4];

    // x chunk: 512 float4, 2 per thread, coalesced (16 threads per 64-float row)
    auto load_x = [&](int c) {
        const int kc = c * KCH;
        #pragma unroll
        for (int s = 0; s < 2; ++s) {
            const int f = s * 256 + tid;   // float4 index: row = f>>4, col4 = f&15
            xreg[s] = *(const float4*)(x + (size_t)(row0 + (f >> 4)) * EMBED + kc + (f & 15) * 4);
        }
    };
    auto store_x = [&](int buf) {
        #pragma unroll
        for (int s = 0; s < 2; ++s) {
            const int f = s * 256 + tid;
            *(float4*)&xs[buf][(f >> 4) * KCH + (f & 15) * 4] = xreg[s];
        }
    };

    // W chunk: 1024 float4, 4 per thread, coalesced
    auto load_w = [&](int c) {
        const int kc = c * KCH;
        #pragma unroll
        for (int r = 0; r < 4; ++r) {
            const int f = r * 256 + tid;   // e = f>>4, col4 = f&15
            wreg[r] = *(const float4*)(W + (size_t)(f >> 4) * EMBED + kc + (f & 15) * 4);
        }
    };
    auto store_w = [&](int buf) {
        #pragma unroll
        for (int r = 0; r < 4; ++r) {
            const int f = r * 256 + tid;
            *(float4*)&ws[buf][(f >> 4) * WPAD + (f & 15) * 4] = wreg[r];
        }
    };

    auto compute = [&](int buf) {
        #pragma unroll
        for (int kk = 0; kk < KCH / 4; ++kk) {
            float4 xv[2], wv[4];
            #pragma unroll
            for (int i = 0; i < 2; ++i)
                xv[i] = *(const float4*)&xs[buf][(rr * 2 + i) * KCH + kk * 4];
            #pragma unroll
            for (int j = 0; j < 4; ++j)
                wv[j] = *(const float4*)&ws[buf][(er + 16 * j) * WPAD + kk * 4];
            #pragma unroll
            for (int i = 0; i < 2; ++i)
                #pragma unroll
                for (int j = 0; j < 4; ++j)
                    acc[i][j] += xv[i].x * wv[j].x + xv[i].y * wv[j].y
                               + xv[i].z * wv[j].z + xv[i].w * wv[j].w;
        }
    };

    // K loop, double-buffered
    load_x(0); load_w(0); store_x(0); store_w(0);
    __syncthreads();
    #pragma unroll 1
    for (int c = 0; c < NCHUNK; c += 2) {
        load_x(c + 1); load_w(c + 1);
        compute(0);
        store_x(1); store_w(1);
        __syncthreads();
        if (c + 2 < NCHUNK) { load_x(c + 2); load_w(c + 2); }
        compute(1);
        if (c + 2 < NCHUNK) { store_x(0); store_w(0); }
        __syncthreads();
    }

    // epilogue: bias, per-row top-3 (top-2 + margin), flags to workspace
    float bl[4];
    #pragma unroll
    for (int j = 0; j < 4; ++j) bl[j] = bias[er + 16 * j];

    #pragma unroll
    for (int i = 0; i < 2; ++i) {
        float v1 = -INFINITY, v2 = -INFINITY, v3 = -INFINITY;
        int i1 = 0, i2 = 0;
        #pragma unroll
        for (int j = 0; j < 4; ++j) {
            const float v = acc[i][j] + bl[j];
            const int e = er + 16 * j;
            if (v > v1)      { v3 = v2; v2 = v1; i2 = i1; v1 = v; i1 = e; }
            else if (v > v2) { v3 = v2; v2 = v;  i2 = e; }
            else if (v > v3) { v3 = v; }
        }
        // butterfly merge of sorted triples across the 16-lane expert group
        #pragma unroll
        for (int m = 1; m <= 8; m <<= 1) {
            const float o1  = __shfl_xor(v1, m, 64);
            const int   oi1 = __shfl_xor(i1, m, 64);
            const float o2  = __shfl_xor(v2, m, 64);
            const int   oi2 = __shfl_xor(i2, m, 64);
            const float o3  = __shfl_xor(v3, m, 64);
            if (o1 > v1) {
                float nv2; int ni2; float nv3;
                if (v1 > o2) { nv2 = v1; ni2 = i1; nv3 = fmaxf(v2, o2); }
                else         { nv2 = o2; ni2 = oi2; nv3 = fmaxf(v1, o3); }
                v1 = o1; i1 = oi1; v2 = nv2; i2 = ni2; v3 = nv3;
            } else {
                if (o1 > v2) { v3 = fmaxf(v2, o2); v2 = o1; i2 = oi1; }
                else         { v3 = fmaxf(v3, o1); }
            }
        }
        if (er == 0) {
            const int row = row0 + rr * 2 + i;
            const float margin = fminf(v1 - v2, v2 - v3);
            flags[row] = (margin < MARGIN_THRESH) ? 1 : 0;   // B overwrites flagged rows
            const float e2  = __expf(v2 - v1);
            const float inv = 1.0f / (1.0f + e2);
            *(float2*)&out[row * 2]              = make_float2(inv, e2 * inv);
            *(float2*)&out[2 * BATCHN + row * 2] = make_float2((float)i1, (float)i2);
        }
    }
}

// ---------------- Kernel B: exact f64 recheck of flagged rows (parallel) ----------------
__global__ __launch_bounds__(NT_B, 2)
void recheck_kernel(const float* __restrict__ x, const float* __restrict__ W,
                    const float* __restrict__ bias, float* __restrict__ out,
                    const int* __restrict__ flags)
{
    __shared__ double sh[NEXP];
    const int tid  = threadIdx.x;
    const int row0 = blockIdx.x * MTILE;
    const int e = tid >> 2, q = tid & 3;     // 4 threads per expert, 512-elem K slices

    #pragma unroll 1
    for (int r = 0; r < MTILE; ++r) {
        if (flags[row0 + r] == 0) continue;  // same address for all threads -> uniform
        const float* xr = x + (size_t)(row0 + r) * EMBED + q * 512;
        const float* wr = W + (size_t)e * EMBED + q * 512;
        double s = 0.0;
        #pragma unroll 4
        for (int k = 0; k < 512; k += 4) {
            const float4 xv = *(const float4*)(xr + k);
            const float4 wv = *(const float4*)(wr + k);
            s += (double)xv.x * (double)wv.x;
            s += (double)xv.y * (double)wv.y;
            s += (double)xv.z * (double)wv.z;
            s += (double)xv.w * (double)wv.w;
        }
        s += __shfl_xor(s, 1, 64);           // reduce the 4 K-slices (contiguous lanes)
        s += __shfl_xor(s, 2, 64);
        if (q == 0) sh[e] = s + (double)bias[e];
        __syncthreads();
        if (tid == 0) {
            double v1 = -1e300, v2 = -1e300; int i1 = 0, i2 = 0;
            for (int ee = 0; ee < NEXP; ++ee) {   // ascending: ties keep lower index
                const double v = sh[ee];
                if (v > v1)      { v2 = v1; i2 = i1; v1 = v; i1 = ee; }
                else if (v > v2) { v2 = v; i2 = ee; }
            }
            const int row = row0 + r;
            const double ex  = exp(v2 - v1);
            const double inv = 1.0 / (1.0 + ex);
            out[row * 2]                  = (float)inv;
            out[row * 2 + 1]              = (float)(ex * inv);
            out[2 * BATCHN + row * 2]     = (float)i1;
            out[2 * BATCHN + row * 2 + 1] = (float)i2;
        }
        __syncthreads();
    }
}

extern "C" void kernel_launch(void* const* d_in, const int* in_sizes, int n_in,
                              void* d_out, int out_size, void* d_ws, size_t ws_size,
                              hipStream_t stream) {
    const float* x = (const float*)d_in[0];
    const float* W = (const float*)d_in[1];
    const float* b = (const float*)d_in[2];
    float* out = (float*)d_out;
    int* flags = (int*)d_ws;                 // 16384 ints, A writes every entry
    gemm_topk_kernel<<<dim3(BATCHN / MTILE), dim3(NT_A), 0, stream>>>(x, W, b, out, flags);
    recheck_kernel <<<dim3(BATCHN / MTILE), dim3(NT_B), 0, stream>>>(x, W, b, out, flags);
}

// Round 7
// 2249.640 us; speedup vs baseline: 1.0582x; 1.0582x over previous
//
#include <hip/hip_runtime.h>
#include <math.h>

#define EMBED   2048
#define NEXP    64
#define BATCHN  16384
#define MTILE   32
#define KCH     64
#define NCHUNK  (EMBED / KCH)   // 32
#define WPAD    68              // W LDS row stride (floats)
#define XPAD    68              // x LDS row stride: rows land on banks {0,8,16,24} -> conflict-free
#define NT_A    256
#define NT_B    256
#define MARGIN_THRESH 4e-4f     // fp32 logit error tail ~1e-5; 40x safety margin

typedef float floatx4 __attribute__((ext_vector_type(4)));  // native vec for nontemporal builtin

// ---------------- Kernel A: fp32 GEMM + top-2 + gates + near-tie flags ----------------
__global__ __launch_bounds__(NT_A, 2)
void gemm_topk_kernel(const float* __restrict__ x, const float* __restrict__ W,
                      const float* __restrict__ bias, float* __restrict__ out,
                      int* __restrict__ flags)
{
    __shared__ __align__(16) float xs[2][MTILE * XPAD];   // 17.4 KB
    __shared__ __align__(16) float ws[2][NEXP * WPAD];    // 34.8 KB

    const int tid  = threadIdx.x;
    const int er   = tid & 15;            // expert group: experts er + 16j, j<4
    const int rr   = tid >> 4;            // row group 0..15: rows rr*2 + i
    // XCD-contiguous swizzle: blocks on XCD k (k = b%8, round-robin dispatch) cover
    // row-tiles [k*64, (k+1)*64) -> one contiguous 16.8 MB x-slice per XCD.
    const int tile = ((blockIdx.x & 7) << 6) | (blockIdx.x >> 3);
    const int row0 = tile * MTILE;

    float acc[2][4] = {};
    floatx4 xreg[2];
    float4 wreg[4];

    // x chunk: 512 float4, 2 per thread, coalesced; non-temporal (streamed once)
    auto load_x = [&](int c) {
        const int kc = c * KCH;
        #pragma unroll
        for (int s = 0; s < 2; ++s) {
            const int f = s * 256 + tid;   // float4 index: row = f>>4, col4 = f&15
            xreg[s] = __builtin_nontemporal_load(
                (const floatx4*)(x + (size_t)(row0 + (f >> 4)) * EMBED + kc + (f & 15) * 4));
        }
    };
    auto store_x = [&](int buf) {
        #pragma unroll
        for (int s = 0; s < 2; ++s) {
            const int f = s * 256 + tid;
            *(floatx4*)&xs[buf][(f >> 4) * XPAD + (f & 15) * 4] = xreg[s];
        }
    };

    // W chunk: 1024 float4, 4 per thread, coalesced; temporal (L2-resident, reused by all blocks)
    auto load_w = [&](int c) {
        const int kc = c * KCH;
        #pragma unroll
        for (int r = 0; r < 4; ++r) {
            const int f = r * 256 + tid;   // e = f>>4, col4 = f&15
            wreg[r] = *(const float4*)(W + (size_t)(f >> 4) * EMBED + kc + (f & 15) * 4);
        }
    };
    auto store_w = [&](int buf) {
        #pragma unroll
        for (int r = 0; r < 4; ++r) {
            const int f = r * 256 + tid;
            *(float4*)&ws[buf][(f >> 4) * WPAD + (f & 15) * 4] = wreg[r];
        }
    };

    auto compute = [&](int buf) {
        #pragma unroll
        for (int kk = 0; kk < KCH / 4; ++kk) {
            float4 xv[2], wv[4];
            #pragma unroll
            for (int i = 0; i < 2; ++i)
                xv[i] = *(const float4*)&xs[buf][(rr * 2 + i) * XPAD + kk * 4];
            #pragma unroll
            for (int j = 0; j < 4; ++j)
                wv[j] = *(const float4*)&ws[buf][(er + 16 * j) * WPAD + kk * 4];
            #pragma unroll
            for (int i = 0; i < 2; ++i)
                #pragma unroll
                for (int j = 0; j < 4; ++j)
                    acc[i][j] += xv[i].x * wv[j].x + xv[i].y * wv[j].y
                               + xv[i].z * wv[j].z + xv[i].w * wv[j].w;
        }
    };

    // K loop, double-buffered
    load_x(0); load_w(0); store_x(0); store_w(0);
    __syncthreads();
    #pragma unroll 1
    for (int c = 0; c < NCHUNK; c += 2) {
        load_x(c + 1); load_w(c + 1);
        compute(0);
        store_x(1); store_w(1);
        __syncthreads();
        if (c + 2 < NCHUNK) { load_x(c + 2); load_w(c + 2); }
        compute(1);
        if (c + 2 < NCHUNK) { store_x(0); store_w(0); }
        __syncthreads();
    }

    // epilogue: bias, per-row top-3 (top-2 + margin), flags to workspace
    float bl[4];
    #pragma unroll
    for (int j = 0; j < 4; ++j) bl[j] = bias[er + 16 * j];

    #pragma unroll
    for (int i = 0; i < 2; ++i) {
        float v1 = -INFINITY, v2 = -INFINITY, v3 = -INFINITY;
        int i1 = 0, i2 = 0;
        #pragma unroll
        for (int j = 0; j < 4; ++j) {
            const float v = acc[i][j] + bl[j];
            const int e = er + 16 * j;
            if (v > v1)      { v3 = v2; v2 = v1; i2 = i1; v1 = v; i1 = e; }
            else if (v > v2) { v3 = v2; v2 = v;  i2 = e; }
            else if (v > v3) { v3 = v; }
        }
        // butterfly merge of sorted triples across the 16-lane expert group
        #pragma unroll
        for (int m = 1; m <= 8; m <<= 1) {
            const float o1  = __shfl_xor(v1, m, 64);
            const int   oi1 = __shfl_xor(i1, m, 64);
            const float o2  = __shfl_xor(v2, m, 64);
            const int   oi2 = __shfl_xor(i2, m, 64);
            const float o3  = __shfl_xor(v3, m, 64);
            if (o1 > v1) {
                float nv2; int ni2; float nv3;
                if (v1 > o2) { nv2 = v1; ni2 = i1; nv3 = fmaxf(v2, o2); }
                else         { nv2 = o2; ni2 = oi2; nv3 = fmaxf(v1, o3); }
                v1 = o1; i1 = oi1; v2 = nv2; i2 = ni2; v3 = nv3;
            } else {
                if (o1 > v2) { v3 = fmaxf(v2, o2); v2 = o1; i2 = oi1; }
                else         { v3 = fmaxf(v3, o1); }
            }
        }
        if (er == 0) {
            const int row = row0 + rr * 2 + i;
            const float margin = fminf(v1 - v2, v2 - v3);
            flags[row] = (margin < MARGIN_THRESH) ? 1 : 0;   // B overwrites flagged rows
            const float e2  = __expf(v2 - v1);
            const float inv = 1.0f / (1.0f + e2);
            *(float2*)&out[row * 2]              = make_float2(inv, e2 * inv);
            *(float2*)&out[2 * BATCHN + row * 2] = make_float2((float)i1, (float)i2);
        }
    }
}

// ---------------- Kernel B: exact f64 recheck of flagged rows (parallel) ----------------
__global__ __launch_bounds__(NT_B, 2)
void recheck_kernel(const float* __restrict__ x, const float* __restrict__ W,
                    const float* __restrict__ bias, float* __restrict__ out,
                    const int* __restrict__ flags)
{
    __shared__ double sh[NEXP];
    const int tid  = threadIdx.x;
    const int row0 = blockIdx.x * MTILE;
    const int e = tid >> 2, q = tid & 3;     // 4 threads per expert, 512-elem K slices

    #pragma unroll 1
    for (int r = 0; r < MTILE; ++r) {
        if (flags[row0 + r] == 0) continue;  // uniform branch (same address for all threads)
        const float* xr = x + (size_t)(row0 + r) * EMBED + q * 512;
        const float* wr = W + (size_t)e * EMBED + q * 512;
        double s = 0.0;
        #pragma unroll 4
        for (int k = 0; k < 512; k += 4) {
            const float4 xv = *(const float4*)(xr + k);
            const float4 wv = *(const float4*)(wr + k);
            s += (double)xv.x * (double)wv.x;
            s += (double)xv.y * (double)wv.y;
            s += (double)xv.z * (double)wv.z;
            s += (double)xv.w * (double)wv.w;
        }
        s += __shfl_xor(s, 1, 64);           // reduce the 4 K-slices (contiguous lanes)
        s += __shfl_xor(s, 2, 64);
        if (q == 0) sh[e] = s + (double)bias[e];
        __syncthreads();
        if (tid == 0) {
            double v1 = -1e300, v2 = -1e300; int i1 = 0, i2 = 0;
            for (int ee = 0; ee < NEXP; ++ee) {   // ascending: ties keep lower index
                const double v = sh[ee];
                if (v > v1)      { v2 = v1; i2 = i1; v1 = v; i1 = ee; }
                else if (v > v2) { v2 = v; i2 = ee; }
            }
            const int row = row0 + r;
            const double ex  = exp(v2 - v1);
            const double inv = 1.0 / (1.0 + ex);
            out[row * 2]                  = (float)inv;
            out[row * 2 + 1]              = (float)(ex * inv);
            out[2 * BATCHN + row * 2]     = (float)i1;
            out[2 * BATCHN + row * 2 + 1] = (float)i2;
        }
        __syncthreads();
    }
}

extern "C" void kernel_launch(void* const* d_in, const int* in_sizes, int n_in,
                              void* d_out, int out_size, void* d_ws, size_t ws_size,
                              hipStream_t stream) {
    const float* x = (const float*)d_in[0];
    const float* W = (const float*)d_in[1];
    const float* b = (const float*)d_in[2];
    float* out = (float*)d_out;
    int* flags = (int*)d_ws;                 // 16384 ints, A writes every entry
    gemm_topk_kernel<<<dim3(BATCHN / MTILE), dim3(NT_A), 0, stream>>>(x, W, b, out, flags);
    recheck_kernel <<<dim3(BATCHN / MTILE), dim3(NT_B), 0, stream>>>(x, W, b, out, flags);
}

// Round 8
// 838.698 us; speedup vs baseline: 2.8384x; 2.6823x over previous
//
#include <hip/hip_runtime.h>
#include <math.h>

#define EMBED   2048
#define NEXP    64
#define BATCHN  16384
#define MTILE   32              // rows per block: 8 row-groups x 4 rows
#define NT_A    128
#define NT_B    256
#define MTILE_B 32
#define MARGIN_THRESH 4e-4f     // fp32 logit error tail ~1e-5; 40x safety margin

// ---------------- Kernel A: LDS-free streaming GEMM + top-2 + gates + flags ----------------
// No __shared__, no barriers: x streams global->VGPR once; W is L2-resident and
// lane-deduplicated (16 lanes share each 16B W segment). Nothing can drain vmcnt.
__global__ __launch_bounds__(NT_A, 4)
void gemm_topk_kernel(const float* __restrict__ x, const float* __restrict__ W,
                      const float* __restrict__ bias, float* __restrict__ out,
                      int* __restrict__ flags)
{
    const int tid  = threadIdx.x;
    const int er   = tid & 15;            // expert group: experts er + 16j, j<4
    const int rr   = tid >> 4;            // row group 0..7: rows rr*4 + i
    const int row0 = blockIdx.x * MTILE;

    const float* xp[4];
    const float* wp[4];
    #pragma unroll
    for (int i = 0; i < 4; ++i) xp[i] = x + (size_t)(row0 + rr * 4 + i) * EMBED;
    #pragma unroll
    for (int j = 0; j < 4; ++j) wp[j] = W + (size_t)(er + 16 * j) * EMBED;

    float acc[4][4] = {};

    #pragma unroll 8
    for (int k = 0; k < EMBED; k += 4) {
        float4 xv[4], wv[4];
        #pragma unroll
        for (int i = 0; i < 4; ++i) xv[i] = *(const float4*)(xp[i] + k);
        #pragma unroll
        for (int j = 0; j < 4; ++j) wv[j] = *(const float4*)(wp[j] + k);
        #pragma unroll
        for (int i = 0; i < 4; ++i)
            #pragma unroll
            for (int j = 0; j < 4; ++j)
                acc[i][j] += xv[i].x * wv[j].x + xv[i].y * wv[j].y
                           + xv[i].z * wv[j].z + xv[i].w * wv[j].w;
    }

    // epilogue: bias, per-row top-3 (top-2 + margin), gates + flags
    float bl[4];
    #pragma unroll
    for (int j = 0; j < 4; ++j) bl[j] = bias[er + 16 * j];

    #pragma unroll
    for (int i = 0; i < 4; ++i) {
        float v1 = -INFINITY, v2 = -INFINITY, v3 = -INFINITY;
        int i1 = 0, i2 = 0;
        #pragma unroll
        for (int j = 0; j < 4; ++j) {        // ascending index -> ties keep lowest index
            const float v = acc[i][j] + bl[j];
            const int e = er + 16 * j;
            if (v > v1)      { v3 = v2; v2 = v1; i2 = i1; v1 = v; i1 = e; }
            else if (v > v2) { v3 = v2; v2 = v;  i2 = e; }
            else if (v > v3) { v3 = v; }
        }
        // butterfly merge of sorted triples across the 16-lane expert group
        #pragma unroll
        for (int m = 1; m <= 8; m <<= 1) {
            const float o1  = __shfl_xor(v1, m, 64);
            const int   oi1 = __shfl_xor(i1, m, 64);
            const float o2  = __shfl_xor(v2, m, 64);
            const int   oi2 = __shfl_xor(i2, m, 64);
            const float o3  = __shfl_xor(v3, m, 64);
            if (o1 > v1) {
                float nv2; int ni2; float nv3;
                if (v1 > o2) { nv2 = v1; ni2 = i1; nv3 = fmaxf(v2, o2); }
                else         { nv2 = o2; ni2 = oi2; nv3 = fmaxf(v1, o3); }
                v1 = o1; i1 = oi1; v2 = nv2; i2 = ni2; v3 = nv3;
            } else {
                if (o1 > v2) { v3 = fmaxf(v2, o2); v2 = o1; i2 = oi1; }
                else         { v3 = fmaxf(v3, o1); }
            }
        }
        if (er == 0) {
            const int row = row0 + rr * 4 + i;
            const float margin = fminf(v1 - v2, v2 - v3);
            flags[row] = (margin < MARGIN_THRESH) ? 1 : 0;   // B overwrites flagged rows
            const float e2  = __expf(v2 - v1);
            const float inv = 1.0f / (1.0f + e2);
            *(float2*)&out[row * 2]              = make_float2(inv, e2 * inv);
            *(float2*)&out[2 * BATCHN + row * 2] = make_float2((float)i1, (float)i2);
        }
    }
}

// ---------------- Kernel B: exact f64 recheck of flagged rows (parallel) ----------------
__global__ __launch_bounds__(NT_B, 2)
void recheck_kernel(const float* __restrict__ x, const float* __restrict__ W,
                    const float* __restrict__ bias, float* __restrict__ out,
                    const int* __restrict__ flags)
{
    __shared__ double sh[NEXP];
    const int tid  = threadIdx.x;
    const int row0 = blockIdx.x * MTILE_B;
    const int e = tid >> 2, q = tid & 3;     // 4 threads per expert, 512-elem K slices

    #pragma unroll 1
    for (int r = 0; r < MTILE_B; ++r) {
        if (flags[row0 + r] == 0) continue;  // uniform branch (same address for all threads)
        const float* xr = x + (size_t)(row0 + r) * EMBED + q * 512;
        const float* wr = W + (size_t)e * EMBED + q * 512;
        double s = 0.0;
        #pragma unroll 4
        for (int k = 0; k < 512; k += 4) {
            const float4 xv = *(const float4*)(xr + k);
            const float4 wv = *(const float4*)(wr + k);
            s += (double)xv.x * (double)wv.x;
            s += (double)xv.y * (double)wv.y;
            s += (double)xv.z * (double)wv.z;
            s += (double)xv.w * (double)wv.w;
        }
        s += __shfl_xor(s, 1, 64);           // reduce the 4 K-slices (contiguous lanes)
        s += __shfl_xor(s, 2, 64);
        if (q == 0) sh[e] = s + (double)bias[e];
        __syncthreads();
        if (tid == 0) {
            double v1 = -1e300, v2 = -1e300; int i1 = 0, i2 = 0;
            for (int ee = 0; ee < NEXP; ++ee) {   // ascending: ties keep lower index
                const double v = sh[ee];
                if (v > v1)      { v2 = v1; i2 = i1; v1 = v; i1 = ee; }
                else if (v > v2) { v2 = v; i2 = ee; }
            }
            const int row = row0 + r;
            const double ex  = exp(v2 - v1);
            const double inv = 1.0 / (1.0 + ex);
            out[row * 2]                  = (float)inv;
            out[row * 2 + 1]              = (float)(ex * inv);
            out[2 * BATCHN + row * 2]     = (float)i1;
            out[2 * BATCHN + row * 2 + 1] = (float)i2;
        }
        __syncthreads();
    }
}

extern "C" void kernel_launch(void* const* d_in, const int* in_sizes, int n_in,
                              void* d_out, int out_size, void* d_ws, size_t ws_size,
                              hipStream_t stream) {
    const float* x = (const float*)d_in[0];
    const float* W = (const float*)d_in[1];
    const float* b = (const float*)d_in[2];
    float* out = (float*)d_out;
    int* flags = (int*)d_ws;                 // 16384 ints, A writes every entry
    gemm_topk_kernel<<<dim3(BATCHN / MTILE),   dim3(NT_A), 0, stream>>>(x, W, b, out, flags);
    recheck_kernel <<<dim3(BATCHN / MTILE_B), dim3(NT_B), 0, stream>>>(x, W, b, out, flags);
}

// Round 9
// 787.891 us; speedup vs baseline: 3.0214x; 1.0645x over previous
//
#include <hip/hip_runtime.h>
#include <math.h>

#define EMBED   2048
#define NEXP    64
#define BATCHN  16384
#define MTILE   8               // rows per block
#define KSLICE  512             // EMBED / 4 waves
#define NT_A    256
#define NT_B    256
#define MTILE_B 32
#define MARGIN_THRESH 4e-4f     // fp32 logit error tail ~1e-5; 40x safety margin

// ---------------- Kernel A: LDS-free K-loop, K split across 4 waves ----------------
// 2048 blocks x 4 waves = 16+ waves/CU (4/SIMD) for latency hiding; the K-loop has
// no barriers (nothing drains vmcnt); one LDS reduction + barrier at the end.
__global__ __launch_bounds__(NT_A, 4)
void gemm_topk_kernel(const float* __restrict__ x, const float* __restrict__ W,
                      const float* __restrict__ bias, float* __restrict__ out,
                      int* __restrict__ flags)
{
    __shared__ float sh[3][64][8];       // waves 1..3 partial accs, 6 KB

    const int tid  = threadIdx.x;
    const int lane = tid & 63;
    const int ks   = tid >> 6;            // wave id = K slice
    const int er   = lane & 15;           // expert group: experts er + 16j, j<4
    const int rg   = (lane >> 4) & 3;     // row group: rows rg*2 + i, i<2
    const int row0 = blockIdx.x * MTILE;

    const float* xp[2];
    const float* wp[4];
    #pragma unroll
    for (int i = 0; i < 2; ++i) xp[i] = x + (size_t)(row0 + rg * 2 + i) * EMBED + ks * KSLICE;
    #pragma unroll
    for (int j = 0; j < 4; ++j) wp[j] = W + (size_t)(er + 16 * j) * EMBED + ks * KSLICE;

    float acc[2][4] = {};

    // software-pipelined: loads for step k+4 issue before FMAs consuming step k
    float4 xv[2], wv[4], xn[2], wn[4];
    #pragma unroll
    for (int i = 0; i < 2; ++i) xv[i] = *(const float4*)(xp[i]);
    #pragma unroll
    for (int j = 0; j < 4; ++j) wv[j] = *(const float4*)(wp[j]);

    #pragma unroll 4
    for (int k = 4; k <= KSLICE; k += 4) {
        if (k < KSLICE) {
            #pragma unroll
            for (int i = 0; i < 2; ++i) xn[i] = *(const float4*)(xp[i] + k);
            #pragma unroll
            for (int j = 0; j < 4; ++j) wn[j] = *(const float4*)(wp[j] + k);
        }
        #pragma unroll
        for (int i = 0; i < 2; ++i)
            #pragma unroll
            for (int j = 0; j < 4; ++j)
                acc[i][j] += xv[i].x * wv[j].x + xv[i].y * wv[j].y
                           + xv[i].z * wv[j].z + xv[i].w * wv[j].w;
        #pragma unroll
        for (int i = 0; i < 2; ++i) xv[i] = xn[i];
        #pragma unroll
        for (int j = 0; j < 4; ++j) wv[j] = wn[j];
    }

    // cross-wave reduction: waves 1..3 publish, wave 0 accumulates
    if (ks > 0) {
        #pragma unroll
        for (int i = 0; i < 2; ++i)
            #pragma unroll
            for (int j = 0; j < 4; ++j)
                sh[ks - 1][lane][i * 4 + j] = acc[i][j];
    }
    __syncthreads();
    if (ks == 0) {
        #pragma unroll
        for (int w = 0; w < 3; ++w)
            #pragma unroll
            for (int i = 0; i < 2; ++i)
                #pragma unroll
                for (int j = 0; j < 4; ++j)
                    acc[i][j] += sh[w][lane][i * 4 + j];

        // epilogue: bias, per-row top-3 (top-2 + margin), gates + flags
        float bl[4];
        #pragma unroll
        for (int j = 0; j < 4; ++j) bl[j] = bias[er + 16 * j];

        #pragma unroll
        for (int i = 0; i < 2; ++i) {
            float v1 = -INFINITY, v2 = -INFINITY, v3 = -INFINITY;
            int i1 = 0, i2 = 0;
            #pragma unroll
            for (int j = 0; j < 4; ++j) {    // ascending index -> ties keep lowest index
                const float v = acc[i][j] + bl[j];
                const int e = er + 16 * j;
                if (v > v1)      { v3 = v2; v2 = v1; i2 = i1; v1 = v; i1 = e; }
                else if (v > v2) { v3 = v2; v2 = v;  i2 = e; }
                else if (v > v3) { v3 = v; }
            }
            // butterfly merge of sorted triples across the 16-lane expert group
            #pragma unroll
            for (int m = 1; m <= 8; m <<= 1) {
                const float o1  = __shfl_xor(v1, m, 64);
                const int   oi1 = __shfl_xor(i1, m, 64);
                const float o2  = __shfl_xor(v2, m, 64);
                const int   oi2 = __shfl_xor(i2, m, 64);
                const float o3  = __shfl_xor(v3, m, 64);
                if (o1 > v1) {
                    float nv2; int ni2; float nv3;
                    if (v1 > o2) { nv2 = v1; ni2 = i1; nv3 = fmaxf(v2, o2); }
                    else         { nv2 = o2; ni2 = oi2; nv3 = fmaxf(v1, o3); }
                    v1 = o1; i1 = oi1; v2 = nv2; i2 = ni2; v3 = nv3;
                } else {
                    if (o1 > v2) { v3 = fmaxf(v2, o2); v2 = o1; i2 = oi1; }
                    else         { v3 = fmaxf(v3, o1); }
                }
            }
            if (er == 0) {
                const int row = row0 + rg * 2 + i;
                const float margin = fminf(v1 - v2, v2 - v3);
                flags[row] = (margin < MARGIN_THRESH) ? 1 : 0;   // B overwrites flagged rows
                const float e2  = __expf(v2 - v1);
                const float inv = 1.0f / (1.0f + e2);
                *(float2*)&out[row * 2]              = make_float2(inv, e2 * inv);
                *(float2*)&out[2 * BATCHN + row * 2] = make_float2((float)i1, (float)i2);
            }
        }
    }
}

// ---------------- Kernel B: exact f64 recheck of flagged rows (parallel) ----------------
__global__ __launch_bounds__(NT_B, 2)
void recheck_kernel(const float* __restrict__ x, const float* __restrict__ W,
                    const float* __restrict__ bias, float* __restrict__ out,
                    const int* __restrict__ flags)
{
    __shared__ double sh[NEXP];
    const int tid  = threadIdx.x;
    const int row0 = blockIdx.x * MTILE_B;
    const int e = tid >> 2, q = tid & 3;     // 4 threads per expert, 512-elem K slices

    #pragma unroll 1
    for (int r = 0; r < MTILE_B; ++r) {
        if (flags[row0 + r] == 0) continue;  // uniform branch (same address for all threads)
        const float* xr = x + (size_t)(row0 + r) * EMBED + q * 512;
        const float* wr = W + (size_t)e * EMBED + q * 512;
        double s = 0.0;
        #pragma unroll 4
        for (int k = 0; k < 512; k += 4) {
            const float4 xv = *(const float4*)(xr + k);
            const float4 wv = *(const float4*)(wr + k);
            s += (double)xv.x * (double)wv.x;
            s += (double)xv.y * (double)wv.y;
            s += (double)xv.z * (double)wv.z;
            s += (double)xv.w * (double)wv.w;
        }
        s += __shfl_xor(s, 1, 64);           // reduce the 4 K-slices (contiguous lanes)
        s += __shfl_xor(s, 2, 64);
        if (q == 0) sh[e] = s + (double)bias[e];
        __syncthreads();
        if (tid == 0) {
            double v1 = -1e300, v2 = -1e300; int i1 = 0, i2 = 0;
            for (int ee = 0; ee < NEXP; ++ee) {   // ascending: ties keep lower index
                const double v = sh[ee];
                if (v > v1)      { v2 = v1; i2 = i1; v1 = v; i1 = ee; }
                else if (v > v2) { v2 = v; i2 = ee; }
            }
            const int row = row0 + r;
            const double ex  = exp(v2 - v1);
            const double inv = 1.0 / (1.0 + ex);
            out[row * 2]                  = (float)inv;
            out[row * 2 + 1]              = (float)(ex * inv);
            out[2 * BATCHN + row * 2]     = (float)i1;
            out[2 * BATCHN + row * 2 + 1] = (float)i2;
        }
        __syncthreads();
    }
}

extern "C" void kernel_launch(void* const* d_in, const int* in_sizes, int n_in,
                              void* d_out, int out_size, void* d_ws, size_t ws_size,
                              hipStream_t stream) {
    const float* x = (const float*)d_in[0];
    const float* W = (const float*)d_in[1];
    const float* b = (const float*)d_in[2];
    float* out = (float*)d_out;
    int* flags = (int*)d_ws;                 // 16384 ints, A writes every entry
    gemm_topk_kernel<<<dim3(BATCHN / MTILE),   dim3(NT_A), 0, stream>>>(x, W, b, out, flags);
    recheck_kernel <<<dim3(BATCHN / MTILE_B), dim3(NT_B), 0, stream>>>(x, W, b, out, flags);
}